// Round 11
// baseline (291.946 us; speedup 1.0000x reference)
//
#include <hip/hip_runtime.h>
#include <cstddef>

#define EMBED 256
#define HEADS 8
#define LEVELS 4
#define POINTS 4
#define NQOUT 384   // 256 offset outputs + 128 attn logits per query row

typedef __attribute__((ext_vector_type(8))) short bf16x8;
typedef __attribute__((ext_vector_type(4))) float f32x4;

__device__ __forceinline__ unsigned short bf16_rn(float x) {
    union { float f; unsigned u; } v; v.f = x;
    const unsigned r = v.u + 0x7fffu + ((v.u >> 16) & 1u);
    return (unsigned short)(r >> 16);
}
__device__ __forceinline__ float bf16_to_f(unsigned short h) {
    union { unsigned u; float f; } v; v.u = (unsigned)h << 16;
    return v.f;
}
// pack 8 floats (2 float4) into hi/lo bf16x8 (split: x = hi + lo + eps)
__device__ __forceinline__ void cvt8(const float4& x, const float4& y,
                                     bf16x8& h, bf16x8& l)
{
    const float f[8] = {x.x, x.y, x.z, x.w, y.x, y.y, y.z, y.w};
    #pragma unroll
    for (int i = 0; i < 8; ++i) {
        const unsigned short hh = bf16_rn(f[i]);
        h[i] = (short)hh;
        l[i] = (short)bf16_rn(f[i] - bf16_to_f(hh));
    }
}

// ---------------------------------------------------------------------------
// Prep v2: convert w_value [256x256] fp32 -> hi/lo bf16 images in MFMA
// FRAGMENT layout: img[kp][j][lane] (1KB per (k-panel, n-frag)); lane l holds
// W[j*16+(l&15)][kp*32+(l>>4)*8 .. +8] as one 16B chunk. The GEMM reads its
// B-fragment with ONE perfectly-coalesced global_load_dwordx4 (1KB/wave-instr)
// — no LDS round-trip at all. 2048 threads, one (row, k-panel) pair each.
// ---------------------------------------------------------------------------
__global__ __launch_bounds__(256) void prep_w(
    const float* __restrict__ w,
    unsigned short* __restrict__ hi, unsigned short* __restrict__ lo)
{
    const int t  = blockIdx.x * 256 + threadIdx.x;   // 0..2047
    const int r  = t >> 3;                           // W row (= output col n)
    const int kp = t & 7;                            // k-panel
    const float* src = w + (size_t)r * 256 + kp * 32;
    #pragma unroll
    for (int c = 0; c < 4; ++c) {                    // k-chunk (lane>>4 = c)
        bf16x8 h, l;
        cvt8(*(const float4*)(src + c * 8), *(const float4*)(src + c * 8 + 4), h, l);
        // byte offset: kp*16KB + (r>>4)*1KB + ((r&15) + 16*c)*16B
        const int off = kp * 16384 + (r >> 4) * 1024 + ((r & 15) + 16 * c) * 16;
        *(bf16x8*)((char*)hi + off) = h;
        *(bf16x8*)((char*)lo + off) = l;
    }
}

// ---------------------------------------------------------------------------
// Value projection v5: barrier-free, LDS-free dataflow MFMA.
// Rounds 8-10 postmortem: the LDS-staged 2-barrier structure plateaued at
// 47-52us with MfmaUtil=VALUBusy=Occ~15% across dbuf/T14 variants — the
// barrier+staging machinery itself is the cost. Here each WAVE owns an
// independent 32x256 output strip (2 m-frags x 16 n-frags of 16x16x32):
// A-frags loaded straight from global (identical per-lane contents to the
// validated LDS path), B-frags read from the pre-arranged fragment image
// (1KB coalesced dwordx4 per frag, L2-resident 256KB). No __syncthreads,
// no LDS, 1662 independent waves. HBM floor ~17us (A read + C write).
// ---------------------------------------------------------------------------
__global__ __launch_bounds__(256) void vproj_mfma_df(
    const float* __restrict__ A,
    const unsigned short* __restrict__ Bhi, const unsigned short* __restrict__ Blo,
    const float* __restrict__ bias, float* __restrict__ C, int M)
{
    const int lane  = threadIdx.x & 63;
    const int wv    = threadIdx.x >> 6;
    const int strip = blockIdx.x * 4 + wv;
    const int m0    = strip * 32;
    if (m0 >= M) return;                     // dummy tail strips (no barriers!)

    // A fragment addressing: row = m0 + frag*16 + (lane&15), k-chunk (lane>>4)*8
    const int rc0 = min(m0 +      (lane & 15), M - 1);
    const int rc1 = min(m0 + 16 + (lane & 15), M - 1);
    const int kc  = (lane >> 4) * 8;
    const float* a0p = A + (size_t)rc0 * 256 + kc;
    const float* a1p = A + (size_t)rc1 * 256 + kc;
    const char*  bhp = (const char*)Bhi + lane * 16;
    const char*  blp = (const char*)Blo + lane * 16;

    f32x4 acc0[16] = {};     // m-frag 0 (rows m0..m0+15), 16 n-frags
    f32x4 acc1[16] = {};     // m-frag 1 (rows m0+16..m0+31)

    for (int kp = 0; kp < 8; ++kp) {
        // A: 2 frags x 8 floats/lane, convert to bf16 hi/lo in registers
        bf16x8 ah0, al0, ah1, al1;
        cvt8(*(const float4*)(a0p + kp * 32), *(const float4*)(a0p + kp * 32 + 4),
             ah0, al0);
        cvt8(*(const float4*)(a1p + kp * 32), *(const float4*)(a1p + kp * 32 + 4),
             ah1, al1);

        // B: 16 n-frags, hi+lo, 1KB coalesced reads; 6 MFMAs per frag
        #pragma unroll
        for (int j = 0; j < 16; ++j) {
            const bf16x8 bh = *(const bf16x8*)(bhp + kp * 16384 + j * 1024);
            const bf16x8 bl = *(const bf16x8*)(blp + kp * 16384 + j * 1024);
            acc0[j] = __builtin_amdgcn_mfma_f32_16x16x32_bf16(ah0, bh, acc0[j], 0, 0, 0);
            acc0[j] = __builtin_amdgcn_mfma_f32_16x16x32_bf16(ah0, bl, acc0[j], 0, 0, 0);
            acc0[j] = __builtin_amdgcn_mfma_f32_16x16x32_bf16(al0, bh, acc0[j], 0, 0, 0);
            acc1[j] = __builtin_amdgcn_mfma_f32_16x16x32_bf16(ah1, bh, acc1[j], 0, 0, 0);
            acc1[j] = __builtin_amdgcn_mfma_f32_16x16x32_bf16(ah1, bl, acc1[j], 0, 0, 0);
            acc1[j] = __builtin_amdgcn_mfma_f32_16x16x32_bf16(al1, bh, acc1[j], 0, 0, 0);
        }
    }

    // epilogue: C/D layout col=lane&15, row=(lane>>4)*4+reg (m89)
    #pragma unroll
    for (int j = 0; j < 16; ++j) {
        const int n  = j * 16 + (lane & 15);
        const float bn = bias[n];
        #pragma unroll
        for (int rr = 0; rr < 4; ++rr) {
            const int mA = m0 + ((lane >> 4) << 2) + rr;
            if (mA < M) C[(size_t)mA * 256 + n] = acc0[j][rr] + bn;
            const int mB = m0 + 16 + ((lane >> 4) << 2) + rr;
            if (mB < M) C[(size_t)mB * 256 + n] = acc1[j][rr] + bn;
        }
    }
}

// ---------------------------------------------------------------------------
// Generic tiled GEMM: C[M,N] = A[M,K] @ B[N,K]^T + bias[N]
// 64x64 tile, 256 threads, 4x4 micro-tile.  (validated rounds 3/5/8/9/10)
// ---------------------------------------------------------------------------
template<int TM, int TN, int TK>
__global__ __launch_bounds__(256) void gemm_abt_bias(
    const float* __restrict__ A, const float* __restrict__ B,
    const float* __restrict__ bias, float* __restrict__ C,
    int M, int N, int K)
{
    __shared__ float As[TK][TM + 4];
    __shared__ float Bs[TK][TN + 4];
    const int tid = threadIdx.x;
    const int m0 = blockIdx.y * TM;
    const int n0 = blockIdx.x * TN;
    const int tx = tid & 15;
    const int ty = tid >> 4;
    const int ar  = tid >> 2;
    const int ac4 = (tid & 3) << 2;

    float acc[4][4] = {};

    for (int k0 = 0; k0 < K; k0 += TK) {
        {
            const int m = m0 + ar;
            float4 va = make_float4(0.f, 0.f, 0.f, 0.f);
            if (m < M) va = *(const float4*)(A + (size_t)m * K + k0 + ac4);
            As[ac4 + 0][ar] = va.x; As[ac4 + 1][ar] = va.y;
            As[ac4 + 2][ar] = va.z; As[ac4 + 3][ar] = va.w;

            const int n = n0 + ar;
            const float4 vb = *(const float4*)(B + (size_t)n * K + k0 + ac4);
            Bs[ac4 + 0][ar] = vb.x; Bs[ac4 + 1][ar] = vb.y;
            Bs[ac4 + 2][ar] = vb.z; Bs[ac4 + 3][ar] = vb.w;
        }
        __syncthreads();

        #pragma unroll
        for (int k = 0; k < TK; ++k) {
            const float4 a4 = *(const float4*)(&As[k][ty << 2]);
            const float4 b4 = *(const float4*)(&Bs[k][tx << 2]);
            const float a[4] = {a4.x, a4.y, a4.z, a4.w};
            const float b[4] = {b4.x, b4.y, b4.z, b4.w};
            #pragma unroll
            for (int i = 0; i < 4; ++i)
                #pragma unroll
                for (int j = 0; j < 4; ++j)
                    acc[i][j] = fmaf(a[i], b[j], acc[i][j]);
        }
        __syncthreads();
    }

    #pragma unroll
    for (int i = 0; i < 4; ++i) {
        const int m = m0 + (ty << 2) + i;
        if (m >= M) continue;
        #pragma unroll
        for (int j = 0; j < 4; ++j) {
            const int n = n0 + (tx << 2) + j;
            C[(size_t)m * N + n] = acc[i][j] + bias[n];
        }
    }
}

// ---------------------------------------------------------------------------
// Fused query GEMM: C[M,384] = query @ [w_off; w_attn]^T + [b_off; b_attn].
// (validated rounds 5/8/9/10)
// ---------------------------------------------------------------------------
__global__ __launch_bounds__(256) void gemm_query_fused(
    const float* __restrict__ A,
    const float* __restrict__ Boff,  const float* __restrict__ Battn,
    const float* __restrict__ boff,  const float* __restrict__ battn,
    float* __restrict__ C, int M, int K)
{
    constexpr int TM = 64, TN = 64, TK = 16;
    __shared__ float As[TK][TM + 4];
    __shared__ float Bs[TK][TN + 4];
    const int tid = threadIdx.x;
    const int m0 = blockIdx.y * TM;
    const int n0 = blockIdx.x * TN;
    const bool isAttn = (n0 >= 256);
    const float* __restrict__ B  = isAttn ? Battn : Boff;
    const float* __restrict__ bv = isAttn ? battn : boff;
    const int nbase = isAttn ? (n0 - 256) : n0;

    const int tx = tid & 15;
    const int ty = tid >> 4;
    const int ar  = tid >> 2;
    const int ac4 = (tid & 3) << 2;

    float acc[4][4] = {};

    for (int k0 = 0; k0 < K; k0 += TK) {
        {
            const int m = m0 + ar;
            float4 va = make_float4(0.f, 0.f, 0.f, 0.f);
            if (m < M) va = *(const float4*)(A + (size_t)m * K + k0 + ac4);
            As[ac4 + 0][ar] = va.x; As[ac4 + 1][ar] = va.y;
            As[ac4 + 2][ar] = va.z; As[ac4 + 3][ar] = va.w;

            const float4 vb = *(const float4*)(B + (size_t)(nbase + ar) * K + k0 + ac4);
            Bs[ac4 + 0][ar] = vb.x; Bs[ac4 + 1][ar] = vb.y;
            Bs[ac4 + 2][ar] = vb.z; Bs[ac4 + 3][ar] = vb.w;
        }
        __syncthreads();

        #pragma unroll
        for (int k = 0; k < TK; ++k) {
            const float4 a4 = *(const float4*)(&As[k][ty << 2]);
            const float4 b4 = *(const float4*)(&Bs[k][tx << 2]);
            const float a[4] = {a4.x, a4.y, a4.z, a4.w};
            const float b[4] = {b4.x, b4.y, b4.z, b4.w};
            #pragma unroll
            for (int i = 0; i < 4; ++i)
                #pragma unroll
                for (int j = 0; j < 4; ++j)
                    acc[i][j] = fmaf(a[i], b[j], acc[i][j]);
        }
        __syncthreads();
    }

    #pragma unroll
    for (int i = 0; i < 4; ++i) {
        const int m = m0 + (ty << 2) + i;
        if (m >= M) continue;
        #pragma unroll
        for (int j = 0; j < 4; ++j) {
            const int nl = (tx << 2) + j;
            C[(size_t)m * NQOUT + n0 + nl] = acc[i][j] + bv[nbase + nl];
        }
    }
}

// ---------------------------------------------------------------------------
// Deformable sampling with fused 16-way softmax. (validated rounds 5/8/9/10)
// ---------------------------------------------------------------------------
__global__ __launch_bounds__(256) void ms_sample_kernel(
    const float* __restrict__ vproj,   // [bs, Lv, 256]
    const float* __restrict__ refp,    // [bs, Lq, 4, 2]
    const float* __restrict__ qout,    // [bs, Lq, 384]
    const int*   __restrict__ shapes,  // [4][2] = (H, W)
    const int*   __restrict__ startix, // [4]
    float* __restrict__ sampled,       // [bs, Lq, 256]
    int Lq, int Lv)
{
    __shared__ float aw_lds[HEADS * LEVELS * POINTS];

    const int bq = blockIdx.x;
    const int b  = bq / Lq;
    const int tid = threadIdx.x;
    const int h = tid >> 5, d = tid & 31;

    const float* vb   = vproj + (size_t)b * Lv * EMBED;
    const float* rowq = qout + (size_t)bq * NQOUT;
    const float* offq = rowq;
    const float* logq = rowq + 256;
    const float* refq = refp + (size_t)bq * LEVELS * 2;

    if (tid < HEADS * LEVELS * POINTS) {
        const float v = logq[tid];
        float m = v;
        #pragma unroll
        for (int s = 8; s > 0; s >>= 1) m = fmaxf(m, __shfl_xor(m, s, 16));
        const float e = __expf(v - m);
        float sum = e;
        #pragma unroll
        for (int s = 8; s > 0; s >>= 1) sum += __shfl_xor(sum, s, 16);
        aw_lds[tid] = e / sum;
    }
    __syncthreads();

    float accv = 0.f;
    #pragma unroll
    for (int l = 0; l < LEVELS; ++l) {
        const int H = shapes[l * 2 + 0];
        const int W = shapes[l * 2 + 1];
        const int st = startix[l];
        const float fW = (float)W, fH = (float)H;
        const float rx = refq[l * 2 + 0];
        const float ry = refq[l * 2 + 1];
        #pragma unroll
        for (int p = 0; p < POINTS; ++p) {
            const int oi = (((h * LEVELS + l) * POINTS) + p) * 2;
            const float ox = offq[oi + 0];
            const float oy = offq[oi + 1];
            const float aw = aw_lds[(h * LEVELS + l) * POINTS + p];
            const float x = (rx + ox / fW) * fW - 0.5f;
            const float y = (ry + oy / fH) * fH - 0.5f;
            const float x0f = floorf(x), y0f = floorf(y);
            const float lx = x - x0f, ly = y - y0f;
            const int x0 = (int)x0f, y0 = (int)y0f;
            float s = 0.f;
            #pragma unroll
            for (int c = 0; c < 4; ++c) {
                const int xi = x0 + (c & 1);
                const int yi = y0 + (c >> 1);
                const float wx = (c & 1) ? lx : 1.f - lx;
                const float wy = (c >> 1) ? ly : 1.f - ly;
                const bool valid = (xi >= 0) && (xi < W) && (yi >= 0) && (yi < H);
                const int xc = min(max(xi, 0), W - 1);
                const int yc = min(max(yi, 0), H - 1);
                const float val = vb[(size_t)(st + yc * W + xc) * EMBED + (h << 5) + d];
                s = fmaf(valid ? wx * wy : 0.f, val, s);
            }
            accv = fmaf(aw, s, accv);
        }
    }
    sampled[(size_t)bq * EMBED + tid] = accv;
}

// ---------------------------------------------------------------------------
extern "C" void kernel_launch(void* const* d_in, const int* in_sizes, int n_in,
                              void* d_out, int out_size, void* d_ws, size_t ws_size,
                              hipStream_t stream)
{
    const float* query   = (const float*)d_in[0];
    const float* refp    = (const float*)d_in[1];
    const float* value   = (const float*)d_in[2];
    const int*   shapes  = (const int*)d_in[3];
    const int*   startix = (const int*)d_in[4];
    const float* w_value = (const float*)d_in[5];
    const float* b_value = (const float*)d_in[6];
    const float* w_off   = (const float*)d_in[7];
    const float* b_off   = (const float*)d_in[8];
    const float* w_attn  = (const float*)d_in[9];
    const float* b_attn  = (const float*)d_in[10];
    const float* w_out   = (const float*)d_in[11];
    const float* b_out   = (const float*)d_in[12];
    float* out = (float*)d_out;

    const int bs = 4;
    const int Lq = in_sizes[0] / (bs * EMBED);   // 900
    const int Lv = in_sizes[2] / (bs * EMBED);   // 13294
    const int BQ = bs * Lq;                      // 3600
    const int M  = bs * Lv;                      // 53176

    float* ws = (float*)d_ws;
    float* vproj   = ws; ws += (size_t)bs * Lv * EMBED;   // 54.5 MB
    float* qoutb   = ws; ws += (size_t)BQ * NQOUT;        // 5.5 MB
    float* sampled = ws; ws += (size_t)BQ * EMBED;        // 3.7 MB
    unsigned short* bhi = (unsigned short*)ws;            // 128 KB
    unsigned short* blo = bhi + 256 * 256;                // 128 KB

    // 0. prep: weight -> fragment-layout hi/lo bf16 images
    hipLaunchKernelGGL(prep_w, dim3(8), dim3(256), 0, stream, w_value, bhi, blo);

    // 1. value projection: barrier-free dataflow MFMA (32 rows per wave)
    {
        const int strips = (M + 31) / 32;            // 1662
        hipLaunchKernelGGL(vproj_mfma_df, dim3((strips + 3) / 4), dim3(256), 0,
                           stream, value, bhi, blo, b_value, vproj, M);
    }
    // 2. fused query GEMM: offsets (N=256) + attn logits (N=128)
    {
        dim3 grid(NQOUT / 64, (BQ + 63) / 64);
        hipLaunchKernelGGL(gemm_query_fused, grid, dim3(256), 0, stream,
                           query, w_off, w_attn, b_off, b_attn, qoutb, BQ, EMBED);
    }
    // 3. deformable sampling with fused softmax
    hipLaunchKernelGGL(ms_sample_kernel, dim3(BQ), dim3(256), 0, stream,
                       vproj, refp, qoutb, shapes, startix, sampled, Lq, Lv);

    // 4. output projection: [BQ,256] @ w_out.T -> d_out
    {
        dim3 grid(EMBED / 64, (BQ + 63) / 64);
        hipLaunchKernelGGL((gemm_abt_bias<64, 64, 16>), grid, dim3(256), 0, stream,
                           sampled, w_out, b_out, out, BQ, EMBED, EMBED);
    }
}